// Round 17
// baseline (114.141 us; speedup 1.0000x reference)
//
#include <hip/hip_runtime.h>
#include <cstdint>
#include <cstddef>

typedef __bf16 bf16_t;
typedef __bf16 bf16x8 __attribute__((ext_vector_type(8)));
typedef __bf16 bf16x4 __attribute__((ext_vector_type(4)));
typedef float  f32x4  __attribute__((ext_vector_type(4)));
typedef unsigned int u32x2 __attribute__((ext_vector_type(2)));
typedef unsigned int u32x4 __attribute__((ext_vector_type(4)));

#define MFMA16(a,b,c) __builtin_amdgcn_mfma_f32_16x16x32_bf16((a),(b),(c),0,0,0)

#if __has_builtin(__builtin_amdgcn_exp2f)
#define EXP2F(x) __builtin_amdgcn_exp2f(x)
#else
#define EXP2F(x) exp2f(x)
#endif

namespace {
constexpr int BATCH = 8;
constexpr int NQ    = 56 * 56;   // 3136 q positions per batch
constexpr int NKV   = 28 * 28;   // 784 kv positions per batch
constexpr int NKVP  = 800;       // kv padded to multiple of 32
// fold 1/sqrt(dk) AND log2(e) into Wq so softmax runs in base-2 (v_exp_f32 native)
constexpr float QSCALE = 0.17677669529663687f * 1.44269504088896340f;

constexpr size_t XB_ELEMS = (size_t)BATCH * 56 * 56 * 256;  // region now unused
constexpr size_t Q_ELEMS  = (size_t)64 * NQ * 32;      // head-major [pair][n][32]
constexpr size_t K_ELEMS  = (size_t)64 * NKVP * 32;    // padded to 800 rows (zeros)
constexpr size_t VT_ELEMS = (size_t)64 * 32 * NKVP;    // [pair][d][kv] padded (zeros)

constexpr size_t XB_OFF  = 0;
constexpr size_t Q_OFF   = XB_OFF + XB_ELEMS * 2;
constexpr size_t K_OFF   = Q_OFF + Q_ELEMS * 2;
constexpr size_t VT_OFF  = K_OFF + K_ELEMS * 2;
constexpr size_t WQT_OFF = VT_OFF + VT_ELEMS * 2;
constexpr size_t WKT_OFF = WQT_OFF + (size_t)65536 * 2;
constexpr size_t WVT_OFF = WKT_OFF + (size_t)262144 * 2;
constexpr size_t WOT_OFF = WVT_OFF + (size_t)262144 * 2;
}

// v_permlane32_swap_b32: a.hi32lanes <-> b.lo32lanes (both operands updated).
// HAZARD-GUARDED: the compiler does not model wait-state hazards inside raw
// asm (VALU-write -> permlane-read, permlane-write -> MFMA-read). s_nop 1 on
// both sides makes the instruction scheduling-independent in the VERIFIED
// rolled-loop body below. History: unguarded+unrolled failed (r7/r9); guarded
// rolled passed (r10/r12/r13/r14/r16); guarded + LDS-staged loop failed (r15)
// — this asm is only trusted inside the exact r13 attn body. Do not reshuffle.
__device__ __forceinline__ void perm32swap(uint32_t& a, uint32_t& b) {
  asm volatile("s_nop 1\n\tv_permlane32_swap_b32 %0, %1\n\ts_nop 1"
               : "+v"(a), "+v"(b));
}

// load 8 consecutive fp32, convert to bf16x8 fragment (RNE — bitwise identical
// to the old prep-pass conversion, so GEMM inputs/outputs are unchanged)
__device__ __forceinline__ bf16x8 ldcvt8(const float* __restrict__ p) {
  float4 a = *(const float4*)p;
  float4 b = *(const float4*)(p + 4);
  bf16x8 r;
  r[0] = (bf16_t)a.x; r[1] = (bf16_t)a.y; r[2] = (bf16_t)a.z; r[3] = (bf16_t)a.w;
  r[4] = (bf16_t)b.x; r[5] = (bf16_t)b.y; r[6] = (bf16_t)b.z; r[7] = (bf16_t)b.w;
  return r;
}

// ---------------- prep: weight transposes + kv-pad zeroing (x stays fp32) ----
// blocks [0,160): weight 64x64 tile transpose via LDS (coalesced both ways).
// blocks [160,224): kv-pad zeroing.

__global__ __launch_bounds__(256) void k_prep(const float* __restrict__ Wq,
                                              const float* __restrict__ Wk,
                                              const float* __restrict__ Wv,
                                              const float* __restrict__ Wo,
                                              bf16_t* __restrict__ Wqt,
                                              bf16_t* __restrict__ Wkt,
                                              bf16_t* __restrict__ Wvt,
                                              bf16_t* __restrict__ Wot,
                                              bf16_t* __restrict__ Kh,
                                              bf16_t* __restrict__ Vt) {
  const int bid = blockIdx.x;
  if (bid < 160) {
    __shared__ float tile[64][65];              // +1 pad: conflict-free columns
    const int wid = bid;                        // 0..159
    const float* w; bf16_t* wt; int K; float scale = 1.f; int local;
    if (wid < 16)       { w = Wq; wt = Wqt; K = 256;  scale = QSCALE; local = wid; }
    else if (wid < 80)  { w = Wk; wt = Wkt; K = 1024; local = wid - 16; }
    else if (wid < 144) { w = Wv; wt = Wvt; K = 1024; local = wid - 80; }
    else                { w = Wo; wt = Wot; K = 256;  local = wid - 144; }
    const int tk = (local >> 2) * 64, tn = (local & 3) * 64;
    const int t = threadIdx.x;
#pragma unroll
    for (int i = 0; i < 16; ++i) {              // coalesced read: row-major
      int e = t + i * 256, kk = e >> 6, nn = e & 63;
      tile[kk][nn] = w[(size_t)(tk + kk) * 256 + tn + nn];
    }
    __syncthreads();
#pragma unroll
    for (int i = 0; i < 16; ++i) {              // coalesced write: 64 bf16 runs
      int e = t + i * 256, nn = e >> 6, kk = e & 63;
      wt[(size_t)(tn + nn) * K + tk + kk] = (bf16_t)(tile[kk][nn] * scale);
    }
    return;
  }
  const int pair = bid - 160;                   // 64 pad blocks
  bf16_t* kp = Kh + (size_t)pair * NKVP * 32 + (size_t)NKV * 32;  // 16 rows x 32
  for (int i = threadIdx.x; i < 512; i += 256) kp[i] = (bf16_t)0.f;
  bf16_t* vp = Vt + (size_t)pair * 32 * NKVP;
  for (int i = threadIdx.x; i < 512; i += 256) {
    int d = i >> 4, c = i & 15;
    vp[(size_t)d * NKVP + NKV + c] = (bf16_t)0.f;
  }
}

// ---------------- merged Q + KV GEMM (fp32 A in-register cvt) ----------------
// One launch, 1176 blocks of 512 threads: [0,784) = Q GEMM, [784,1176) = KV.
// A is the fp32 input x, converted in-register (bitwise == old xb path).
// XCD-grouped decodes keep the 4x/8x A re-reads L2-resident per XCD even at
// fp32 width (q: 3.2 MB, kv: 3.2 MB working sets < 4 MB per-XCD L2) — this is
// what made r4's fp32-direct fail (cross-XCD scatter -> 106 MB HBM) and makes
// it safe now. Eliminates the 38.5 MB x->bf16 staging pass entirely.

__global__ __launch_bounds__(512) void k_gemm_qkv(const float* __restrict__ X,
                                                  const bf16_t* __restrict__ Wqt,
                                                  const bf16_t* __restrict__ Wkt,
                                                  const bf16_t* __restrict__ Wvt,
                                                  bf16_t* __restrict__ Qh,
                                                  bf16_t* __restrict__ Kh,
                                                  bf16_t* __restrict__ Vt) {
  __shared__ __align__(16) char Blds[64 * 1024];  // 64 KB (q path uses first 32 KB)
  const int t = threadIdx.x;
  const int lane = t & 63, wv = t >> 6;
  const int lq = lane & 15, grp = lane >> 4;

  if (blockIdx.x < 784) {
    // ---------------- Q GEMM ----------------
    const int w = ((int)blockIdx.x & 7) * 98 + ((int)blockIdx.x >> 3);
    const int m0 = (w >> 2) * 128 + wv * 16;
    const int n0 = (w & 3) * 64;

#pragma unroll
    for (int i = 0; i < 4; ++i) {
      int c = t + i * 512;                 // 2048 chunks of 16B
      int r = c >> 5, cb = (c & 31) << 4;
      bf16x8 v = *(const bf16x8*)(Wqt + (size_t)(n0 + r) * 256 + (cb >> 1));
      *(bf16x8*)(Blds + r * 512 + (cb ^ ((r & 7) << 4))) = v;
    }
    __syncthreads();

    const float* Arow = X + (size_t)(m0 + lq) * 256 + grp * 8;
    f32x4 acc[4] = {};
#pragma unroll
    for (int kk = 0; kk < 8; ++kk) {
      bf16x8 af = ldcvt8(Arow + kk * 32);
#pragma unroll
      for (int nt = 0; nt < 4; ++nt) {
        const int r = nt * 16 + lq;
        bf16x8 bfr = *(const bf16x8*)(Blds + r * 512 + ((kk * 64 + grp * 16) ^ ((r & 7) << 4)));
        acc[nt] = MFMA16(af, bfr, acc[nt]);
      }
    }

    const int grow = m0 + grp * 4;          // quad of rows, same batch (3136%4==0)
    const int b = grow / NQ, pos = grow - b * NQ;
#pragma unroll
    for (int nt = 0; nt < 4; ++nt) {
      const int n = n0 + nt * 16 + lq;
      const int h = n >> 5, d = n & 31;
      bf16_t* dst = Qh + ((size_t)(b * 8 + h) * NQ + pos) * 32 + d;
#pragma unroll
      for (int j = 0; j < 4; ++j) dst[(size_t)j * 32] = (bf16_t)acc[nt][j];
    }
    return;
  }

  // ---------------- KV GEMM (2x2 stride-2 conv over K=1024) ----------------
  const int bid2 = (int)blockIdx.x - 784;
  const int w = (bid2 & 7) * 49 + (bid2 >> 3);
  const int rem = w & 7;
  const int mode = rem & 1;
  const int n0 = (rem >> 1) * 64;
  const int mt = (w >> 3) * 128 + wv * 16;
  const bf16_t* Wt = mode ? Wvt : Wkt;

  const int grow = mt + lq;              // 0..6271, all valid (6272 = 8*784)
  const int b = grow / NKV, pos = grow - b * NKV;
  const int pi = pos / 28, pj = pos % 28;
  const float* x4[4];
#pragma unroll
  for (int hw = 0; hw < 4; ++hw) {
    const int h_ = hw >> 1, w_ = hw & 1;
    x4[hw] = X + ((size_t)((b * 56 + 2 * pi + h_) * 56) + 2 * pj + w_) * 256 + grp * 8;
  }

  f32x4 acc[4] = {};
#pragma unroll
  for (int half = 0; half < 2; ++half) {
    if (half) __syncthreads();           // all reads of phase-0 B done
#pragma unroll
    for (int i = 0; i < 8; ++i) {
      int c = t + i * 512;               // 4096 chunks of 16B
      int r = c >> 6, cb = (c & 63) << 4;
      bf16x8 v = *(const bf16x8*)(Wt + (size_t)(n0 + r) * 1024 + half * 512 + (cb >> 1));
      *(bf16x8*)(Blds + r * 1024 + (cb ^ ((r & 7) << 4))) = v;
    }
    __syncthreads();
#pragma unroll
    for (int kk = 0; kk < 16; ++kk) {
      const int gk = half * 16 + kk;
      const int hw = gk >> 3, kkk = gk & 7;
      bf16x8 af = ldcvt8(x4[hw] + kkk * 32);
#pragma unroll
      for (int nt = 0; nt < 4; ++nt) {
        const int r = nt * 16 + lq;
        bf16x8 bfr = *(const bf16x8*)(Blds + r * 1024 + ((kk * 64 + grp * 16) ^ ((r & 7) << 4)));
        acc[nt] = MFMA16(af, bfr, acc[nt]);
      }
    }
  }

  const int mbase = mt + grp * 4;        // 784%4==0: quad within one batch
  const int b2 = mbase / NKV, pos2 = mbase - b2 * NKV;
  if (mode == 0) {
#pragma unroll
    for (int nt = 0; nt < 4; ++nt) {
      const int n = n0 + nt * 16 + lq;
      const int h = n >> 5, d = n & 31;
      bf16_t* dst = Kh + ((size_t)(b2 * 8 + h) * NKVP + pos2) * 32 + d;
#pragma unroll
      for (int j = 0; j < 4; ++j) dst[(size_t)j * 32] = (bf16_t)acc[nt][j];
    }
  } else {
#pragma unroll
    for (int nt = 0; nt < 4; ++nt) {
      const int n = n0 + nt * 16 + lq;
      const int h = n >> 5, d = n & 31;
      bf16x4 v;
#pragma unroll
      for (int j = 0; j < 4; ++j) v[j] = (bf16_t)acc[nt][j];
      *(bf16x4*)&Vt[((size_t)(b2 * 8 + h) * 32 + d) * NKVP + pos2] = v;
    }
  }
}

// ---------------- fused attention (r13-verified body, FROZEN) ----------------
// 1D grid 1568, XCD-swizzled decode: xcd = wg&7 owns y-groups {2*xcd, 2*xcd+1}
// -> 8 pairs (800 KB K/V) L2-resident per XCD. Block 256 = 4 waves; wave wv
// owns pair ygrp*4+wv, 32 q rows. Swapped QK^T with PERMUTED K-row loads; two
// hazard-guarded v_permlane32_swap_b32 build the PV B-fragment in registers.
// f32 ps lsum + end shuffles. SINGLE accumulators (r14 split-acc: -1.2us).
// Depth-1 A/B double-buffered K/V pipeline in a ROLLED loop (#pragma unroll 1).
// No max-tracking (scores tiny -> exact softmax with m=0); phantom kv rows are
// zeros -> exp2(0)=1 in lsum (subtract 16) and 0 in PV.
// FROZEN: passed r10/r12/r13/r16; every structural reshuffle (full unroll
// r7/r9, LDS staging r15) broke numerics via permlane scheduling sensitivity.

__global__ __launch_bounds__(256) void k_attn(const bf16_t* __restrict__ Qh,
                                              const bf16_t* __restrict__ Kh,
                                              const bf16_t* __restrict__ Vt,
                                              bf16_t* __restrict__ att) {
  const int lane = threadIdx.x & 63, wv = threadIdx.x >> 6;
  const int lq = lane & 15, grp = lane >> 4;
  const int wg = blockIdx.x;                 // 0..1567
  const int idx = wg >> 3;                   // 0..195
  const int ygrp = (wg & 7) * 2 + idx / 98;  // 0..15
  const int pair = ygrp * 4 + wv;
  const int q0 = (idx % 98) * 32;

  const bf16_t* Qbase = Qh + ((size_t)pair * NQ + q0) * 32;
  bf16x8 qf[2];
#pragma unroll
  for (int t = 0; t < 2; ++t)
    qf[t] = *(const bf16x8*)(Qbase + (size_t)(t * 16 + lq) * 32 + grp * 8);

  const int prow = (lq & 3) | ((lq & 4) << 1) | ((lq & 8) >> 1);  // quad swap 1<->2
  const bf16_t* Kb = Kh + (size_t)pair * NKVP * 32 + (size_t)prow * 32 + grp * 8;
  const bf16_t* Vb = Vt + (size_t)pair * 32 * NKVP + grp * 8;

  const f32x4 fz = {0.f, 0.f, 0.f, 0.f};
  f32x4 ps[2] = {fz, fz};
  f32x4 ot[2][2] = {{fz, fz}, {fz, fz}};

  bf16x8 Ak0, Ak1, Av0, Av1, Bk0, Bk1, Bv0, Bv1;

#define LOADF(P, CH) do { const int kv0_ = (CH) * 32;                          \
    P##k0 = *(const bf16x8*)(Kb + (size_t)kv0_ * 32);                          \
    P##k1 = *(const bf16x8*)(Kb + (size_t)(kv0_ + 16) * 32);                   \
    P##v0 = *(const bf16x8*)(Vb + (size_t)lq * NKVP + kv0_);                   \
    P##v1 = *(const bf16x8*)(Vb + (size_t)(16 + lq) * NKVP + kv0_); } while (0)

#define COMPUTE(P) do {                                                        \
    _Pragma("unroll")                                                          \
    for (int t = 0; t < 2; ++t) {                                              \
      f32x4 s0 = MFMA16(P##k0, qf[t], fz);                                     \
      f32x4 s1 = MFMA16(P##k1, qf[t], fz);                                     \
      f32x4 e0, e1;                                                            \
      _Pragma("unroll")                                                        \
      for (int j = 0; j < 4; ++j) { e0[j] = EXP2F(s0[j]); e1[j] = EXP2F(s1[j]); } \
      ps[t] += e0 + e1;                                                        \
      bf16x4 pa, pb;                                                           \
      _Pragma("unroll")                                                        \
      for (int j = 0; j < 4; ++j) { pa[j] = (bf16_t)e0[j]; pb[j] = (bf16_t)e1[j]; } \
      u32x2 ua = __builtin_bit_cast(u32x2, pa);                                \
      u32x2 ub = __builtin_bit_cast(u32x2, pb);                                \
      uint32_t x0 = ua[0], x1 = ua[1], y0 = ub[0], y1 = ub[1];                 \
      perm32swap(x0, y0);                                                      \
      perm32swap(x1, y1);                                                      \
      u32x4 pfu = {x0, x1, y0, y1};                                            \
      bf16x8 pf = __builtin_bit_cast(bf16x8, pfu);                             \
      ot[t][0] = MFMA16(P##v0, pf, ot[t][0]);                                  \
      ot[t][1] = MFMA16(P##v1, pf, ot[t][1]);                                  \
    } } while (0)

  LOADF(A, 0);
#pragma unroll 1
  for (int i = 0; i < 12; ++i) {   // ROLLED: full unroll of this loop fails (r7/r9)
    LOADF(B, 2 * i + 1);
    COMPUTE(A);
    LOADF(A, 2 * i + 2);
    COMPUTE(B);
  }
  COMPUTE(A);                              // chunk 24
#undef LOADF
#undef COMPUTE

#pragma unroll
  for (int t = 0; t < 2; ++t) {
    float l = ps[t][0] + ps[t][1] + ps[t][2] + ps[t][3];
    l += __shfl_xor(l, 16, 64);
    l += __shfl_xor(l, 32, 64);
    const float inv = 1.f / (l - 16.f);        // remove 16 phantom exp2(0)=1 terms
    bf16_t* obase = att + ((size_t)pair * NQ + q0 + t * 16 + lq) * 32;
    bf16x4 o0, o1;
#pragma unroll
    for (int j = 0; j < 4; ++j) {
      o0[j] = (bf16_t)(ot[t][0][j] * inv);
      o1[j] = (bf16_t)(ot[t][1][j] * inv);
    }
    *(bf16x4*)(obase + grp * 4) = o0;
    *(bf16x4*)(obase + 16 + grp * 4) = o1;
  }
}

// ---------------- output projection + bias (LDS-stationary B, fp32 out) ------
// A is head-major att[pair][n][32]; 1D grid 784, XCD-grouped decode (4x A
// re-read becomes L2-resident). Block 512 (8 waves x 16 rows).

__global__ __launch_bounds__(512) void k_gemm_proj(const bf16_t* __restrict__ A,
                                                   const bf16_t* __restrict__ Wt,
                                                   const float* __restrict__ bias,
                                                   float* __restrict__ out) {
  __shared__ __align__(16) char Blds[64 * 512];   // 32 KB
  const int t = threadIdx.x;
  const int lane = t & 63, wv = t >> 6;
  const int lq = lane & 15, grp = lane >> 4;
  const int w = (blockIdx.x & 7) * 98 + (blockIdx.x >> 3);  // xcd-contiguous id
  const int m0 = (w >> 2) * 128 + wv * 16;
  const int n0 = (w & 3) * 64;

#pragma unroll
  for (int i = 0; i < 4; ++i) {
    int c = t + i * 512;
    int r = c >> 5, cb = (c & 31) << 4;
    bf16x8 v = *(const bf16x8*)(Wt + (size_t)(n0 + r) * 256 + (cb >> 1));
    *(bf16x8*)(Blds + r * 512 + (cb ^ ((r & 7) << 4))) = v;
  }
  __syncthreads();

  const int gm = m0 + lq;
  const int b = gm / NQ, pos = gm - b * NQ;
  f32x4 acc[4] = {};
#pragma unroll
  for (int kk = 0; kk < 8; ++kk) {       // kk = head index
    bf16x8 af = *(const bf16x8*)(A + ((size_t)(b * 8 + kk) * NQ + pos) * 32 + grp * 8);
#pragma unroll
    for (int nt = 0; nt < 4; ++nt) {
      const int r = nt * 16 + lq;
      bf16x8 bfr = *(const bf16x8*)(Blds + r * 512 + ((kk * 64 + grp * 16) ^ ((r & 7) << 4)));
      acc[nt] = MFMA16(af, bfr, acc[nt]);
    }
  }

  const int mrow = m0 + grp * 4;
#pragma unroll
  for (int nt = 0; nt < 4; ++nt) {
    const int nn = n0 + nt * 16 + lq;
    const float bb = bias[nn];
#pragma unroll
    for (int j = 0; j < 4; ++j)
      out[(size_t)(mrow + j) * 256 + nn] = acc[nt][j] + bb;
  }
}

// ---------------- launch ----------------

extern "C" void kernel_launch(void* const* d_in, const int* in_sizes, int n_in,
                              void* d_out, int out_size, void* d_ws, size_t ws_size,
                              hipStream_t stream) {
  const float* x  = (const float*)d_in[0];
  const float* Wq = (const float*)d_in[1];
  const float* Wk = (const float*)d_in[2];
  const float* Wv = (const float*)d_in[3];
  const float* Wo = (const float*)d_in[4];
  const float* bo = (const float*)d_in[5];
  float* out = (float*)d_out;

  char* ws = (char*)d_ws;
  bf16_t* Qh  = (bf16_t*)(ws + Q_OFF);
  bf16_t* att = Qh;  // alias: each attn wave reads only its own Q rows, then writes same rows
  bf16_t* Kh  = (bf16_t*)(ws + K_OFF);
  bf16_t* Vt  = (bf16_t*)(ws + VT_OFF);
  bf16_t* Wqt = (bf16_t*)(ws + WQT_OFF);
  bf16_t* Wkt = (bf16_t*)(ws + WKT_OFF);
  bf16_t* Wvt = (bf16_t*)(ws + WVT_OFF);
  bf16_t* Wot = (bf16_t*)(ws + WOT_OFF);

  k_prep<<<224, 256, 0, stream>>>(Wq, Wk, Wv, Wo, Wqt, Wkt, Wvt, Wot, Kh, Vt);
  k_gemm_qkv<<<1176, 512, 0, stream>>>(x, Wqt, Wkt, Wvt, Qh, Kh, Vt);
  k_attn<<<1568, 256, 0, stream>>>(Qh, Kh, Vt, att);
  k_gemm_proj<<<784, 512, 0, stream>>>(att, Wot, bo, out);
}

// Round 18
// 99.208 us; speedup vs baseline: 1.1505x; 1.1505x over previous
//
#include <hip/hip_runtime.h>
#include <cstdint>
#include <cstddef>

typedef __bf16 bf16_t;
typedef __bf16 bf16x8 __attribute__((ext_vector_type(8)));
typedef __bf16 bf16x4 __attribute__((ext_vector_type(4)));
typedef float  f32x4  __attribute__((ext_vector_type(4)));
typedef unsigned int u32x2 __attribute__((ext_vector_type(2)));
typedef unsigned int u32x4 __attribute__((ext_vector_type(4)));

#define MFMA16(a,b,c) __builtin_amdgcn_mfma_f32_16x16x32_bf16((a),(b),(c),0,0,0)

#if __has_builtin(__builtin_amdgcn_exp2f)
#define EXP2F(x) __builtin_amdgcn_exp2f(x)
#else
#define EXP2F(x) exp2f(x)
#endif

namespace {
constexpr int BATCH = 8;
constexpr int NQ    = 56 * 56;   // 3136 q positions per batch
constexpr int NKV   = 28 * 28;   // 784 kv positions per batch
constexpr int NKVP  = 800;       // kv padded to multiple of 32
// fold 1/sqrt(dk) AND log2(e) into Wq so softmax runs in base-2 (v_exp_f32 native)
constexpr float QSCALE = 0.17677669529663687f * 1.44269504088896340f;

constexpr size_t XB_ELEMS = (size_t)BATCH * 56 * 56 * 256;
constexpr size_t Q_ELEMS  = (size_t)64 * NQ * 32;      // head-major [pair][n][32]
constexpr size_t K_ELEMS  = (size_t)64 * NKVP * 32;    // padded to 800 rows (zeros)
constexpr size_t VT_ELEMS = (size_t)64 * 32 * NKVP;    // [pair][d][kv] padded (zeros)

constexpr size_t XB_OFF  = 0;
constexpr size_t Q_OFF   = XB_OFF + XB_ELEMS * 2;
constexpr size_t K_OFF   = Q_OFF + Q_ELEMS * 2;
constexpr size_t VT_OFF  = K_OFF + K_ELEMS * 2;
constexpr size_t WQT_OFF = VT_OFF + VT_ELEMS * 2;
constexpr size_t WKT_OFF = WQT_OFF + (size_t)65536 * 2;
constexpr size_t WVT_OFF = WKT_OFF + (size_t)262144 * 2;
constexpr size_t WOT_OFF = WVT_OFF + (size_t)262144 * 2;
}

// v_permlane32_swap_b32: a.hi32lanes <-> b.lo32lanes (both operands updated).
// HAZARD-GUARDED: the compiler does not model wait-state hazards inside raw
// asm (VALU-write -> permlane-read, permlane-write -> MFMA-read). s_nop 1 on
// both sides makes the instruction scheduling-independent in the VERIFIED
// rolled-loop body below. History: unguarded+unrolled failed (r7/r9); guarded
// rolled passed (r10/r12/r13/r14/r16); guarded + LDS-staged loop failed (r15)
// — this asm is only trusted inside the exact r13 attn body. Do not reshuffle.
__device__ __forceinline__ void perm32swap(uint32_t& a, uint32_t& b) {
  asm volatile("s_nop 1\n\tv_permlane32_swap_b32 %0, %1\n\ts_nop 1"
               : "+v"(a), "+v"(b));
}

// ---------------- fused prep: x->bf16, weight transposes, kv-pad zeroing -----
// blocks [0,6272): x cvt (coalesced float4).
// blocks [6272,6432): weight 64x64 tile transpose via LDS (coalesced both ways).
// blocks [6432,6496): kv-pad zeroing.
// NOTE (r17 lesson): the x->bf16 staging pass pays 38.5 MB HBM (~7us) to make
// the GEMM A working sets bf16-width; q+kv segments run CONCURRENTLY on each
// XCD, so their combined A set must fit 4 MB L2 (bf16: 3.2 MB fits; fp32:
// 6.5 MB thrashed -> r17 regression). Keep the staging.

__global__ __launch_bounds__(256) void k_prep(const float* __restrict__ x,
                                              const float* __restrict__ Wq,
                                              const float* __restrict__ Wk,
                                              const float* __restrict__ Wv,
                                              const float* __restrict__ Wo,
                                              bf16_t* __restrict__ xb,
                                              bf16_t* __restrict__ Wqt,
                                              bf16_t* __restrict__ Wkt,
                                              bf16_t* __restrict__ Wvt,
                                              bf16_t* __restrict__ Wot,
                                              bf16_t* __restrict__ Kh,
                                              bf16_t* __restrict__ Vt) {
  const int bid = blockIdx.x;
  if (bid < 6272) {
    int i = bid * 256 + threadIdx.x;            // exactly XB_ELEMS/4 threads
    float4 v = ((const float4*)x)[i];
    bf16x4 o;
    o[0] = (bf16_t)v.x; o[1] = (bf16_t)v.y; o[2] = (bf16_t)v.z; o[3] = (bf16_t)v.w;
    ((bf16x4*)xb)[i] = o;
    return;
  }
  if (bid < 6432) {
    __shared__ float tile[64][65];              // +1 pad: conflict-free columns
    const int wid = bid - 6272;                 // 0..159
    const float* w; bf16_t* wt; int K; float scale = 1.f; int local;
    if (wid < 16)       { w = Wq; wt = Wqt; K = 256;  scale = QSCALE; local = wid; }
    else if (wid < 80)  { w = Wk; wt = Wkt; K = 1024; local = wid - 16; }
    else if (wid < 144) { w = Wv; wt = Wvt; K = 1024; local = wid - 80; }
    else                { w = Wo; wt = Wot; K = 256;  local = wid - 144; }
    const int tk = (local >> 2) * 64, tn = (local & 3) * 64;
    const int t = threadIdx.x;
#pragma unroll
    for (int i = 0; i < 16; ++i) {              // coalesced read: row-major
      int e = t + i * 256, kk = e >> 6, nn = e & 63;
      tile[kk][nn] = w[(size_t)(tk + kk) * 256 + tn + nn];
    }
    __syncthreads();
#pragma unroll
    for (int i = 0; i < 16; ++i) {              // coalesced write: 64 bf16 runs
      int e = t + i * 256, nn = e >> 6, kk = e & 63;
      wt[(size_t)(tn + nn) * K + tk + kk] = (bf16_t)(tile[kk][nn] * scale);
    }
    return;
  }
  const int pair = bid - 6432;                  // 64 pad blocks
  bf16_t* kp = Kh + (size_t)pair * NKVP * 32 + (size_t)NKV * 32;  // 16 rows x 32
  for (int i = threadIdx.x; i < 512; i += 256) kp[i] = (bf16_t)0.f;
  bf16_t* vp = Vt + (size_t)pair * 32 * NKVP;
  for (int i = threadIdx.x; i < 512; i += 256) {
    int d = i >> 4, c = i & 15;
    vp[(size_t)d * NKVP + NKV + c] = (bf16_t)0.f;
  }
}

// ---------------- merged Q + KV GEMM (LDS-stationary B) ----------------------
// One launch, 1176 blocks of 512 threads: [0,784) = Q GEMM, [784,1176) = KV.
// kv blocks overlap q's drain tail (independent work, both read xb).
// 784 % 8 == 0 keeps both segments' (&7) XCD decodes aligned.

__global__ __launch_bounds__(512) void k_gemm_qkv(const bf16_t* __restrict__ xb,
                                                  const bf16_t* __restrict__ Wqt,
                                                  const bf16_t* __restrict__ Wkt,
                                                  const bf16_t* __restrict__ Wvt,
                                                  bf16_t* __restrict__ Qh,
                                                  bf16_t* __restrict__ Kh,
                                                  bf16_t* __restrict__ Vt) {
  __shared__ __align__(16) char Blds[64 * 1024];  // 64 KB (q path uses first 32 KB)
  const int t = threadIdx.x;
  const int lane = t & 63, wv = t >> 6;
  const int lq = lane & 15, grp = lane >> 4;

  if (blockIdx.x < 784) {
    // ---------------- Q GEMM ----------------
    const int w = ((int)blockIdx.x & 7) * 98 + ((int)blockIdx.x >> 3);
    const int m0 = (w >> 2) * 128 + wv * 16;
    const int n0 = (w & 3) * 64;

#pragma unroll
    for (int i = 0; i < 4; ++i) {
      int c = t + i * 512;                 // 2048 chunks of 16B
      int r = c >> 5, cb = (c & 31) << 4;
      bf16x8 v = *(const bf16x8*)(Wqt + (size_t)(n0 + r) * 256 + (cb >> 1));
      *(bf16x8*)(Blds + r * 512 + (cb ^ ((r & 7) << 4))) = v;
    }
    __syncthreads();

    const bf16_t* Arow = xb + (size_t)(m0 + lq) * 256 + grp * 8;
    f32x4 acc[4] = {};
#pragma unroll
    for (int kk = 0; kk < 8; ++kk) {
      bf16x8 af = *(const bf16x8*)(Arow + kk * 32);
#pragma unroll
      for (int nt = 0; nt < 4; ++nt) {
        const int r = nt * 16 + lq;
        bf16x8 bfr = *(const bf16x8*)(Blds + r * 512 + ((kk * 64 + grp * 16) ^ ((r & 7) << 4)));
        acc[nt] = MFMA16(af, bfr, acc[nt]);
      }
    }

    const int grow = m0 + grp * 4;          // quad of rows, same batch (3136%4==0)
    const int b = grow / NQ, pos = grow - b * NQ;
#pragma unroll
    for (int nt = 0; nt < 4; ++nt) {
      const int n = n0 + nt * 16 + lq;
      const int h = n >> 5, d = n & 31;
      bf16_t* dst = Qh + ((size_t)(b * 8 + h) * NQ + pos) * 32 + d;
#pragma unroll
      for (int j = 0; j < 4; ++j) dst[(size_t)j * 32] = (bf16_t)acc[nt][j];
    }
    return;
  }

  // ---------------- KV GEMM (2x2 stride-2 conv over K=1024) ----------------
  const int bid2 = (int)blockIdx.x - 784;
  const int w = (bid2 & 7) * 49 + (bid2 >> 3);
  const int rem = w & 7;
  const int mode = rem & 1;
  const int n0 = (rem >> 1) * 64;
  const int mt = (w >> 3) * 128 + wv * 16;
  const bf16_t* Wt = mode ? Wvt : Wkt;

  const int grow = mt + lq;              // 0..6271, all valid (6272 = 8*784)
  const int b = grow / NKV, pos = grow - b * NKV;
  const int pi = pos / 28, pj = pos % 28;
  const bf16_t* x4[4];
#pragma unroll
  for (int hw = 0; hw < 4; ++hw) {
    const int h_ = hw >> 1, w_ = hw & 1;
    x4[hw] = xb + ((size_t)((b * 56 + 2 * pi + h_) * 56) + 2 * pj + w_) * 256 + grp * 8;
  }

  f32x4 acc[4] = {};
#pragma unroll
  for (int half = 0; half < 2; ++half) {
    if (half) __syncthreads();           // all reads of phase-0 B done
#pragma unroll
    for (int i = 0; i < 8; ++i) {
      int c = t + i * 512;               // 4096 chunks of 16B
      int r = c >> 6, cb = (c & 63) << 4;
      bf16x8 v = *(const bf16x8*)(Wt + (size_t)(n0 + r) * 1024 + half * 512 + (cb >> 1));
      *(bf16x8*)(Blds + r * 1024 + (cb ^ ((r & 7) << 4))) = v;
    }
    __syncthreads();
#pragma unroll
    for (int kk = 0; kk < 16; ++kk) {
      const int gk = half * 16 + kk;
      const int hw = gk >> 3, kkk = gk & 7;
      bf16x8 af = *(const bf16x8*)(x4[hw] + kkk * 32);
#pragma unroll
      for (int nt = 0; nt < 4; ++nt) {
        const int r = nt * 16 + lq;
        bf16x8 bfr = *(const bf16x8*)(Blds + r * 1024 + ((kk * 64 + grp * 16) ^ ((r & 7) << 4)));
        acc[nt] = MFMA16(af, bfr, acc[nt]);
      }
    }
  }

  const int mbase = mt + grp * 4;        // 784%4==0: quad within one batch
  const int b2 = mbase / NKV, pos2 = mbase - b2 * NKV;
  if (mode == 0) {
#pragma unroll
    for (int nt = 0; nt < 4; ++nt) {
      const int n = n0 + nt * 16 + lq;
      const int h = n >> 5, d = n & 31;
      bf16_t* dst = Kh + ((size_t)(b2 * 8 + h) * NKVP + pos2) * 32 + d;
#pragma unroll
      for (int j = 0; j < 4; ++j) dst[(size_t)j * 32] = (bf16_t)acc[nt][j];
    }
  } else {
#pragma unroll
    for (int nt = 0; nt < 4; ++nt) {
      const int n = n0 + nt * 16 + lq;
      const int h = n >> 5, d = n & 31;
      bf16x4 v;
#pragma unroll
      for (int j = 0; j < 4; ++j) v[j] = (bf16_t)acc[nt][j];
      *(bf16x4*)&Vt[((size_t)(b2 * 8 + h) * 32 + d) * NKVP + pos2] = v;
    }
  }
}

// ---------------- fused attention (r13-verified body, FROZEN) ----------------
// 1D grid 1568, XCD-swizzled decode: xcd = wg&7 owns y-groups {2*xcd, 2*xcd+1}
// -> 8 pairs (800 KB K/V) L2-resident per XCD. Block 256 = 4 waves; wave wv
// owns pair ygrp*4+wv, 32 q rows. Swapped QK^T with PERMUTED K-row loads; two
// hazard-guarded v_permlane32_swap_b32 build the PV B-fragment in registers.
// f32 ps lsum + end shuffles. SINGLE accumulators (r14 split-acc: -1.2us).
// Depth-1 A/B double-buffered K/V pipeline in a ROLLED loop (#pragma unroll 1).
// No max-tracking (scores tiny -> exact softmax with m=0); phantom kv rows are
// zeros -> exp2(0)=1 in lsum (subtract 16) and 0 in PV.
// FROZEN: passed r10/r12/r13/r16; every structural reshuffle (full unroll
// r7/r9, LDS staging r15) broke numerics via permlane scheduling sensitivity.

__global__ __launch_bounds__(256) void k_attn(const bf16_t* __restrict__ Qh,
                                              const bf16_t* __restrict__ Kh,
                                              const bf16_t* __restrict__ Vt,
                                              bf16_t* __restrict__ att) {
  const int lane = threadIdx.x & 63, wv = threadIdx.x >> 6;
  const int lq = lane & 15, grp = lane >> 4;
  const int wg = blockIdx.x;                 // 0..1567
  const int idx = wg >> 3;                   // 0..195
  const int ygrp = (wg & 7) * 2 + idx / 98;  // 0..15
  const int pair = ygrp * 4 + wv;
  const int q0 = (idx % 98) * 32;

  const bf16_t* Qbase = Qh + ((size_t)pair * NQ + q0) * 32;
  bf16x8 qf[2];
#pragma unroll
  for (int t = 0; t < 2; ++t)
    qf[t] = *(const bf16x8*)(Qbase + (size_t)(t * 16 + lq) * 32 + grp * 8);

  const int prow = (lq & 3) | ((lq & 4) << 1) | ((lq & 8) >> 1);  // quad swap 1<->2
  const bf16_t* Kb = Kh + (size_t)pair * NKVP * 32 + (size_t)prow * 32 + grp * 8;
  const bf16_t* Vb = Vt + (size_t)pair * 32 * NKVP + grp * 8;

  const f32x4 fz = {0.f, 0.f, 0.f, 0.f};
  f32x4 ps[2] = {fz, fz};
  f32x4 ot[2][2] = {{fz, fz}, {fz, fz}};

  bf16x8 Ak0, Ak1, Av0, Av1, Bk0, Bk1, Bv0, Bv1;

#define LOADF(P, CH) do { const int kv0_ = (CH) * 32;                          \
    P##k0 = *(const bf16x8*)(Kb + (size_t)kv0_ * 32);                          \
    P##k1 = *(const bf16x8*)(Kb + (size_t)(kv0_ + 16) * 32);                   \
    P##v0 = *(const bf16x8*)(Vb + (size_t)lq * NKVP + kv0_);                   \
    P##v1 = *(const bf16x8*)(Vb + (size_t)(16 + lq) * NKVP + kv0_); } while (0)

#define COMPUTE(P) do {                                                        \
    _Pragma("unroll")                                                          \
    for (int t = 0; t < 2; ++t) {                                              \
      f32x4 s0 = MFMA16(P##k0, qf[t], fz);                                     \
      f32x4 s1 = MFMA16(P##k1, qf[t], fz);                                     \
      f32x4 e0, e1;                                                            \
      _Pragma("unroll")                                                        \
      for (int j = 0; j < 4; ++j) { e0[j] = EXP2F(s0[j]); e1[j] = EXP2F(s1[j]); } \
      ps[t] += e0 + e1;                                                        \
      bf16x4 pa, pb;                                                           \
      _Pragma("unroll")                                                        \
      for (int j = 0; j < 4; ++j) { pa[j] = (bf16_t)e0[j]; pb[j] = (bf16_t)e1[j]; } \
      u32x2 ua = __builtin_bit_cast(u32x2, pa);                                \
      u32x2 ub = __builtin_bit_cast(u32x2, pb);                                \
      uint32_t x0 = ua[0], x1 = ua[1], y0 = ub[0], y1 = ub[1];                 \
      perm32swap(x0, y0);                                                      \
      perm32swap(x1, y1);                                                      \
      u32x4 pfu = {x0, x1, y0, y1};                                            \
      bf16x8 pf = __builtin_bit_cast(bf16x8, pfu);                             \
      ot[t][0] = MFMA16(P##v0, pf, ot[t][0]);                                  \
      ot[t][1] = MFMA16(P##v1, pf, ot[t][1]);                                  \
    } } while (0)

  LOADF(A, 0);
#pragma unroll 1
  for (int i = 0; i < 12; ++i) {   // ROLLED: full unroll of this loop fails (r7/r9)
    LOADF(B, 2 * i + 1);
    COMPUTE(A);
    LOADF(A, 2 * i + 2);
    COMPUTE(B);
  }
  COMPUTE(A);                              // chunk 24
#undef LOADF
#undef COMPUTE

#pragma unroll
  for (int t = 0; t < 2; ++t) {
    float l = ps[t][0] + ps[t][1] + ps[t][2] + ps[t][3];
    l += __shfl_xor(l, 16, 64);
    l += __shfl_xor(l, 32, 64);
    const float inv = 1.f / (l - 16.f);        // remove 16 phantom exp2(0)=1 terms
    bf16_t* obase = att + ((size_t)pair * NQ + q0 + t * 16 + lq) * 32;
    bf16x4 o0, o1;
#pragma unroll
    for (int j = 0; j < 4; ++j) {
      o0[j] = (bf16_t)(ot[t][0][j] * inv);
      o1[j] = (bf16_t)(ot[t][1][j] * inv);
    }
    *(bf16x4*)(obase + grp * 4) = o0;
    *(bf16x4*)(obase + 16 + grp * 4) = o1;
  }
}

// ---------------- output projection + bias (LDS-stationary B, fp32 out) ------
// A is head-major att[pair][n][32]; 1D grid 784, XCD-grouped decode (4x A
// re-read becomes L2-resident). Block 512 (8 waves x 16 rows).

__global__ __launch_bounds__(512) void k_gemm_proj(const bf16_t* __restrict__ A,
                                                   const bf16_t* __restrict__ Wt,
                                                   const float* __restrict__ bias,
                                                   float* __restrict__ out) {
  __shared__ __align__(16) char Blds[64 * 512];   // 32 KB
  const int t = threadIdx.x;
  const int lane = t & 63, wv = t >> 6;
  const int lq = lane & 15, grp = lane >> 4;
  const int w = (blockIdx.x & 7) * 98 + (blockIdx.x >> 3);  // xcd-contiguous id
  const int m0 = (w >> 2) * 128 + wv * 16;
  const int n0 = (w & 3) * 64;

#pragma unroll
  for (int i = 0; i < 4; ++i) {
    int c = t + i * 512;
    int r = c >> 5, cb = (c & 31) << 4;
    bf16x8 v = *(const bf16x8*)(Wt + (size_t)(n0 + r) * 256 + (cb >> 1));
    *(bf16x8*)(Blds + r * 512 + (cb ^ ((r & 7) << 4))) = v;
  }
  __syncthreads();

  const int gm = m0 + lq;
  const int b = gm / NQ, pos = gm - b * NQ;
  f32x4 acc[4] = {};
#pragma unroll
  for (int kk = 0; kk < 8; ++kk) {       // kk = head index
    bf16x8 af = *(const bf16x8*)(A + ((size_t)(b * 8 + kk) * NQ + pos) * 32 + grp * 8);
#pragma unroll
    for (int nt = 0; nt < 4; ++nt) {
      const int r = nt * 16 + lq;
      bf16x8 bfr = *(const bf16x8*)(Blds + r * 512 + ((kk * 64 + grp * 16) ^ ((r & 7) << 4)));
      acc[nt] = MFMA16(af, bfr, acc[nt]);
    }
  }

  const int mrow = m0 + grp * 4;
#pragma unroll
  for (int nt = 0; nt < 4; ++nt) {
    const int nn = n0 + nt * 16 + lq;
    const float bb = bias[nn];
#pragma unroll
    for (int j = 0; j < 4; ++j)
      out[(size_t)(mrow + j) * 256 + nn] = acc[nt][j] + bb;
  }
}

// ---------------- launch ----------------

extern "C" void kernel_launch(void* const* d_in, const int* in_sizes, int n_in,
                              void* d_out, int out_size, void* d_ws, size_t ws_size,
                              hipStream_t stream) {
  const float* x  = (const float*)d_in[0];
  const float* Wq = (const float*)d_in[1];
  const float* Wk = (const float*)d_in[2];
  const float* Wv = (const float*)d_in[3];
  const float* Wo = (const float*)d_in[4];
  const float* bo = (const float*)d_in[5];
  float* out = (float*)d_out;

  char* ws = (char*)d_ws;
  bf16_t* xb  = (bf16_t*)(ws + XB_OFF);
  bf16_t* Qh  = (bf16_t*)(ws + Q_OFF);
  bf16_t* att = Qh;  // alias: each attn wave reads only its own Q rows, then writes same rows
  bf16_t* Kh  = (bf16_t*)(ws + K_OFF);
  bf16_t* Vt  = (bf16_t*)(ws + VT_OFF);
  bf16_t* Wqt = (bf16_t*)(ws + WQT_OFF);
  bf16_t* Wkt = (bf16_t*)(ws + WKT_OFF);
  bf16_t* Wvt = (bf16_t*)(ws + WVT_OFF);
  bf16_t* Wot = (bf16_t*)(ws + WOT_OFF);

  k_prep<<<6496, 256, 0, stream>>>(x, Wq, Wk, Wv, Wo, xb, Wqt, Wkt, Wvt, Wot, Kh, Vt);
  k_gemm_qkv<<<1176, 512, 0, stream>>>(xb, Wqt, Wkt, Wvt, Qh, Kh, Vt);
  k_attn<<<1568, 256, 0, stream>>>(Qh, Kh, Vt, att);
  k_gemm_proj<<<784, 512, 0, stream>>>(att, Wot, bo, out);
}